// Round 1
// baseline (131.490 us; speedup 1.0000x reference)
//
#include <hip/hip_runtime.h>
#include <hip/hip_bf16.h>

#define B_ 4
#define Q_ 256
#define K_ 1024
#define D_ 256

__device__ __forceinline__ float fexp2(float x) {
    float r; asm("v_exp_f32 %0, %1" : "=v"(r) : "v"(x)); return r;
}
__device__ __forceinline__ float frcp(float x) {
    float r; asm("v_rcp_f32 %0, %1" : "=v"(r) : "v"(x)); return r;
}

// out[M,256] = A[M,256] @ W[256,256]   (row-major, grid.x = M/64, grid.y = 4)
__global__ __launch_bounds__(256) void proj_kernel(const float* __restrict__ A,
                                                   const float* __restrict__ W,
                                                   float* __restrict__ out) {
    __shared__ float As[16][65];
    __shared__ float Ws[16][64];
    const int t = threadIdx.x;
    const int tx = t & 15, ty = t >> 4;
    const int m0 = blockIdx.x * 64, n0 = blockIdx.y * 64;
    const int ar = t >> 2, ac = (t & 3) * 4;   // A staging: 64 rows x 16 cols
    const int wr = t >> 4, wc = (t & 15) * 4;  // W staging: 16 rows x 64 cols
    float c[4][4] = {};
    for (int kb = 0; kb < 256; kb += 16) {
        __syncthreads();
        float4 av = *(const float4*)(A + (size_t)(m0 + ar) * 256 + kb + ac);
        As[ac + 0][ar] = av.x; As[ac + 1][ar] = av.y;
        As[ac + 2][ar] = av.z; As[ac + 3][ar] = av.w;
        *(float4*)(&Ws[wr][wc]) = *(const float4*)(W + (size_t)(kb + wr) * 256 + n0 + wc);
        __syncthreads();
#pragma unroll
        for (int kk = 0; kk < 16; ++kk) {
            float4 bv = *(const float4*)(&Ws[kk][tx * 4]);
#pragma unroll
            for (int i = 0; i < 4; ++i) {
                float a = As[kk][ty * 4 + i];
                c[i][0] = fmaf(a, bv.x, c[i][0]);
                c[i][1] = fmaf(a, bv.y, c[i][1]);
                c[i][2] = fmaf(a, bv.z, c[i][2]);
                c[i][3] = fmaf(a, bv.w, c[i][3]);
            }
        }
    }
#pragma unroll
    for (int i = 0; i < 4; ++i) {
        float4 o = make_float4(c[i][0], c[i][1], c[i][2], c[i][3]);
        *(float4*)(out + (size_t)(m0 + ty * 4 + i) * 256 + n0 + tx * 4) = o;
    }
}

// One block per (b, 4 q's). 512 threads = 8 waves.
// Wave w handles e-chunk [w*32, w*32+32); lane = k within the 64-k tile.
__global__ __launch_bounds__(512, 2) void attn_kernel(const float* __restrict__ qp,
                                                      const float* __restrict__ kp,
                                                      const float* __restrict__ v,
                                                      const int* __restrict__ mask,
                                                      const float* __restrict__ wv,
                                                      float* __restrict__ out) {
    __shared__ float4 s_kp[64 * 65];        // 66,560 B : kp tile, row stride 65 f4
    __shared__ float  s_sc[4][1024];        // 16,384 B : scores then probs
    __shared__ float  s_red[8][4][64];      //  8,192 B : cross-wave partials

    const int tid  = threadIdx.x;
    const int lane = tid & 63;
    const int wave = tid >> 6;
    const int b  = blockIdx.x >> 6;
    const int q0 = (blockIdx.x & 63) * 4;

    // ---- preload qp rows (this wave's e-chunk) and wv chunk into registers ----
    float qp_r[4][32];
    float wv_r[32];
    {
        const int e0 = wave * 32;
#pragma unroll
        for (int q = 0; q < 4; ++q) {
            const float4* p = (const float4*)(qp + (size_t)(b * Q_ + q0 + q) * D_ + e0);
#pragma unroll
            for (int i = 0; i < 8; ++i) {
                float4 x = p[i];
                qp_r[q][i * 4 + 0] = x.x; qp_r[q][i * 4 + 1] = x.y;
                qp_r[q][i * 4 + 2] = x.z; qp_r[q][i * 4 + 3] = x.w;
            }
        }
        const float4* pw = (const float4*)(wv + e0);
#pragma unroll
        for (int i = 0; i < 8; ++i) {
            float4 x = pw[i];
            wv_r[i * 4 + 0] = x.x; wv_r[i * 4 + 1] = x.y;
            wv_r[i * 4 + 2] = x.z; wv_r[i * 4 + 3] = x.w;
        }
    }

    // ---- score computation over 16 k-tiles of 64 ----
    for (int kt = 0; kt < 16; ++kt) {
        __syncthreads();   // s_kp / s_red free for reuse
        {
            const float4* src = (const float4*)(kp + (size_t)(b * K_ + kt * 64) * D_);
#pragma unroll
            for (int i = 0; i < 8; ++i) {
                int f = tid + i * 512;                      // coalesced
                s_kp[(f >> 6) * 65 + (f & 63)] = src[f];    // padded rows
            }
        }
        __syncthreads();
        float a0 = 0.f, a1 = 0.f, a2 = 0.f, a3 = 0.f;
        const float4* krow = s_kp + lane * 65 + wave * 8;
#pragma unroll
        for (int t4 = 0; t4 < 8; ++t4) {
            float4 kv = krow[t4];
            float kc[4] = {kv.x, kv.y, kv.z, kv.w};
#pragma unroll
            for (int j = 0; j < 4; ++j) {
                const int e = t4 * 4 + j;
                const float kvj = kc[j];
                const float w = wv_r[e];
                {
                    float x = qp_r[0][e] + kvj;
                    float r = frcp(fexp2(x * 2.885390082f) + 1.0f);
                    a0 = fmaf(w, fmaf(-2.f, r, 1.f), a0);
                }
                {
                    float x = qp_r[1][e] + kvj;
                    float r = frcp(fexp2(x * 2.885390082f) + 1.0f);
                    a1 = fmaf(w, fmaf(-2.f, r, 1.f), a1);
                }
                {
                    float x = qp_r[2][e] + kvj;
                    float r = frcp(fexp2(x * 2.885390082f) + 1.0f);
                    a2 = fmaf(w, fmaf(-2.f, r, 1.f), a2);
                }
                {
                    float x = qp_r[3][e] + kvj;
                    float r = frcp(fexp2(x * 2.885390082f) + 1.0f);
                    a3 = fmaf(w, fmaf(-2.f, r, 1.f), a3);
                }
            }
        }
        s_red[wave][0][lane] = a0;
        s_red[wave][1][lane] = a1;
        s_red[wave][2][lane] = a2;
        s_red[wave][3][lane] = a3;
        __syncthreads();
        if (tid < 256) {
            const int q = tid >> 6, kl = tid & 63;
            float s = 0.f;
#pragma unroll
            for (int w = 0; w < 8; ++w) s += s_red[w][q][kl];
            s_sc[q][kt * 64 + kl] = s;
        }
    }
    __syncthreads();

    // ---- masked softmax: wave w < 4 handles q = w ----
    if (wave < 4) {
        const int q = wave;
        float sc[16];
        float mx = -3.0e38f;
#pragma unroll
        for (int j = 0; j < 16; ++j) {
            const int k = lane + j * 64;
            float s = s_sc[q][k];
            s = mask[b * K_ + k] ? s : -3.0e38f;
            sc[j] = s;
            mx = fmaxf(mx, s);
        }
#pragma unroll
        for (int off = 32; off > 0; off >>= 1) mx = fmaxf(mx, __shfl_xor(mx, off));
        float sum = 0.f;
#pragma unroll
        for (int j = 0; j < 16; ++j) {
            float e = fexp2((sc[j] - mx) * 1.44269504f);
            sc[j] = e;
            sum += e;
        }
#pragma unroll
        for (int off = 32; off > 0; off >>= 1) sum += __shfl_xor(sum, off);
        const float inv = frcp(sum);
#pragma unroll
        for (int j = 0; j < 16; ++j) s_sc[q][lane + j * 64] = sc[j] * inv;
    }
    __syncthreads();

    // ---- PV: thread -> (d-float4 = tid&63, k-group = tid>>6 covering 128 k) ----
    {
        const int dl = tid & 63;
        const int kq = tid >> 6;
        float4 o0 = {0, 0, 0, 0}, o1 = {0, 0, 0, 0}, o2 = {0, 0, 0, 0}, o3 = {0, 0, 0, 0};
        const float4* v4 = (const float4*)(v + (size_t)b * K_ * D_);
#pragma unroll 4
        for (int k = kq * 128; k < kq * 128 + 128; ++k) {
            float4 vv = v4[k * 64 + dl];
            float p0 = s_sc[0][k], p1 = s_sc[1][k], p2 = s_sc[2][k], p3 = s_sc[3][k];
            o0.x = fmaf(p0, vv.x, o0.x); o0.y = fmaf(p0, vv.y, o0.y);
            o0.z = fmaf(p0, vv.z, o0.z); o0.w = fmaf(p0, vv.w, o0.w);
            o1.x = fmaf(p1, vv.x, o1.x); o1.y = fmaf(p1, vv.y, o1.y);
            o1.z = fmaf(p1, vv.z, o1.z); o1.w = fmaf(p1, vv.w, o1.w);
            o2.x = fmaf(p2, vv.x, o2.x); o2.y = fmaf(p2, vv.y, o2.y);
            o2.z = fmaf(p2, vv.z, o2.z); o2.w = fmaf(p2, vv.w, o2.w);
            o3.x = fmaf(p3, vv.x, o3.x); o3.y = fmaf(p3, vv.y, o3.y);
            o3.z = fmaf(p3, vv.z, o3.z); o3.w = fmaf(p3, vv.w, o3.w);
        }
        // s_kp no longer read by anyone (last reads were before the softmax barrier)
        float4* s_pv = s_kp;
        s_pv[(kq * 4 + 0) * 64 + dl] = o0;
        s_pv[(kq * 4 + 1) * 64 + dl] = o1;
        s_pv[(kq * 4 + 2) * 64 + dl] = o2;
        s_pv[(kq * 4 + 3) * 64 + dl] = o3;
        __syncthreads();
        if (tid < 256) {
            const int q = tid >> 6, c = tid & 63;
            float4 s = {0, 0, 0, 0};
#pragma unroll
            for (int g = 0; g < 8; ++g) {
                float4 x = s_pv[(g * 4 + q) * 64 + c];
                s.x += x.x; s.y += x.y; s.z += x.z; s.w += x.w;
            }
            *(float4*)(out + (size_t)(b * Q_ + q0 + q) * D_ + c * 4) = s;
        }
    }
}

extern "C" void kernel_launch(void* const* d_in, const int* in_sizes, int n_in,
                              void* d_out, int out_size, void* d_ws, size_t ws_size,
                              hipStream_t stream) {
    const float* q    = (const float*)d_in[0];
    const float* k    = (const float*)d_in[1];
    const float* v    = (const float*)d_in[2];
    const int*   mask = (const int*)d_in[3];
    const float* Wq   = (const float*)d_in[4];
    const float* Wk   = (const float*)d_in[5];
    const float* wv   = (const float*)d_in[6];
    float* out = (float*)d_out;

    float* qp = (float*)d_ws;                        // [B,Q,D]  1 MB
    float* kp = qp + (size_t)B_ * Q_ * D_;           // [B,K,D]  4 MB

    proj_kernel<<<dim3(B_ * Q_ / 64, 4), 256, 0, stream>>>(q, Wq, qp);
    proj_kernel<<<dim3(B_ * K_ / 64, 4), 256, 0, stream>>>(k, Wk, kp);
    attn_kernel<<<dim3(B_ * (Q_ / 4)), 512, 0, stream>>>(qp, kp, v, mask, wv, out);
}

// Round 2
// 89.668 us; speedup vs baseline: 1.4664x; 1.4664x over previous
//
#include <hip/hip_runtime.h>
#include <hip/hip_bf16.h>

#define B_ 4
#define Q_ 256
#define K_ 1024
#define D_ 256

__device__ __forceinline__ float fexp2(float x) {
    float r; asm("v_exp_f32 %0, %1" : "=v"(r) : "v"(x)); return r;
}
__device__ __forceinline__ float frcp(float x) {
    float r; asm("v_rcp_f32 %0, %1" : "=v"(r) : "v"(x)); return r;
}

// Per-batch compaction of valid k indices. Grid = B, 64 threads (1 wave).
__global__ void compact_kernel(const int* __restrict__ mask,
                               ushort* __restrict__ kidx, int* __restrict__ nvalid) {
    const int b = blockIdx.x, lane = threadIdx.x;
    const int* m = mask + b * K_;
    const int base = lane * 16;
    int cnt = 0;
#pragma unroll
    for (int i = 0; i < 16; ++i) cnt += (m[base + i] != 0);
    int inc = cnt;
#pragma unroll
    for (int d = 1; d < 64; d <<= 1) {
        int t = __shfl_up(inc, d);
        if (lane >= d) inc += t;
    }
    const int total = __shfl(inc, 63);
    int pos = inc - cnt;                     // exclusive prefix
    ushort* kb = kidx + b * K_;
    for (int i = 0; i < 16; ++i) {
        int k = base + i;
        if (m[k] != 0) kb[pos++] = (ushort)k;
    }
    for (int j = total + lane; j < K_; j += 64) kb[j] = 0;  // safe tail
    if (lane == 0) nvalid[b] = total;
}

// out[M,256] = scale * (A[M,256] @ W[256,256])
__global__ __launch_bounds__(256) void proj_kernel(const float* __restrict__ A,
                                                   const float* __restrict__ W,
                                                   float* __restrict__ out,
                                                   float scale) {
    __shared__ float As[16][65];
    __shared__ float Ws[16][64];
    const int t = threadIdx.x;
    const int tx = t & 15, ty = t >> 4;
    const int m0 = blockIdx.x * 64, n0 = blockIdx.y * 64;
    const int ar = t >> 2, ac = (t & 3) * 4;
    const int wr = t >> 4, wc = (t & 15) * 4;
    float c[4][4] = {};
    for (int kb = 0; kb < 256; kb += 16) {
        __syncthreads();
        float4 av = *(const float4*)(A + (size_t)(m0 + ar) * 256 + kb + ac);
        As[ac + 0][ar] = av.x; As[ac + 1][ar] = av.y;
        As[ac + 2][ar] = av.z; As[ac + 3][ar] = av.w;
        float4 wvv = *(const float4*)(W + (size_t)(kb + wr) * 256 + n0 + wc);
        wvv.x *= scale; wvv.y *= scale; wvv.z *= scale; wvv.w *= scale;
        *(float4*)(&Ws[wr][wc]) = wvv;
        __syncthreads();
#pragma unroll
        for (int kk = 0; kk < 16; ++kk) {
            float4 bv = *(const float4*)(&Ws[kk][tx * 4]);
#pragma unroll
            for (int i = 0; i < 4; ++i) {
                float a = As[kk][ty * 4 + i];
                c[i][0] = fmaf(a, bv.x, c[i][0]);
                c[i][1] = fmaf(a, bv.y, c[i][1]);
                c[i][2] = fmaf(a, bv.z, c[i][2]);
                c[i][3] = fmaf(a, bv.w, c[i][3]);
            }
        }
    }
#pragma unroll
    for (int i = 0; i < 4; ++i) {
        float4 o = make_float4(c[i][0], c[i][1], c[i][2], c[i][3]);
        *(float4*)(out + (size_t)(m0 + ty * 4 + i) * 256 + n0 + tx * 4) = o;
    }
}

// One block per (b, 2 q's). 512 threads = 8 waves, 2 blocks/CU.
// Wave w handles e-chunk [w*32, w*32+32); lane = compacted-k within 64-k tile.
// qp/kp pre-scaled by 2*log2(e), so score = -2 * sum_e wv_e / (exp2(qp+kp)+1)
// (softmax-shift-invariant constant dropped).
__global__ __launch_bounds__(512, 4) void attn_kernel(const float* __restrict__ qp,
                                                      const float* __restrict__ kp,
                                                      const float* __restrict__ v,
                                                      const ushort* __restrict__ kidx_g,
                                                      const int* __restrict__ nvalid_g,
                                                      const float* __restrict__ wv,
                                                      float* __restrict__ out) {
    __shared__ float4 s_kp[64 * 65];        // 66,560 B : kp tile, row stride 65 f4
    __shared__ float  s_sc[2][1024];        //  8,192 B : scores then probs
    __shared__ float  s_red[8][2][64];      //  4,096 B : cross-wave partials
    __shared__ ushort s_kidx[1024];         //  2,048 B : compacted k indices
    __shared__ int    s_nv;

    const int tid  = threadIdx.x;
    const int lane = tid & 63;
    const int wave = tid >> 6;

    // bijective XCD swizzle (gridDim.x = 512, 512 % 8 == 0)
    int bid = blockIdx.x;
    bid = (bid & 7) * 64 + (bid >> 3);
    const int b  = bid >> 7;
    const int q0 = (bid & 127) * 2;

    s_kidx[tid]       = kidx_g[b * K_ + tid];
    s_kidx[tid + 512] = kidx_g[b * K_ + tid + 512];
    if (tid == 0) s_nv = nvalid_g[b];

    // preload qp rows (this wave's e-chunk) and wv chunk into registers
    float qp_r[2][32];
    float wv_r[32];
    {
        const int e0 = wave * 32;
#pragma unroll
        for (int q = 0; q < 2; ++q) {
            const float4* p = (const float4*)(qp + (size_t)(b * Q_ + q0 + q) * D_ + e0);
#pragma unroll
            for (int i = 0; i < 8; ++i) {
                float4 x = p[i];
                qp_r[q][i * 4 + 0] = x.x; qp_r[q][i * 4 + 1] = x.y;
                qp_r[q][i * 4 + 2] = x.z; qp_r[q][i * 4 + 3] = x.w;
            }
        }
        const float4* pw = (const float4*)(wv + e0);
#pragma unroll
        for (int i = 0; i < 8; ++i) {
            float4 x = pw[i];
            wv_r[i * 4 + 0] = x.x; wv_r[i * 4 + 1] = x.y;
            wv_r[i * 4 + 2] = x.z; wv_r[i * 4 + 3] = x.w;
        }
    }
    __syncthreads();
    const int nv = s_nv;
    const int ntiles = (nv + 63) >> 6;

    // ---- scores over compacted-k tiles of 64 ----
    for (int kt = 0; kt < ntiles; ++kt) {
        __syncthreads();
        {
            const float4* srcb = (const float4*)(kp + (size_t)b * K_ * D_);
#pragma unroll
            for (int i = 0; i < 8; ++i) {
                int row = wave + i * 8;               // wave-uniform
                int col = lane;
                int gr = s_kidx[kt * 64 + row];       // broadcast read
                s_kp[row * 65 + col] = srcb[(size_t)gr * 64 + col];
            }
        }
        __syncthreads();
        float a0 = 0.f, a1 = 0.f;
        const float4* krow = s_kp + lane * 65 + wave * 8;
#pragma unroll
        for (int t4 = 0; t4 < 8; ++t4) {
            float4 kv = krow[t4];
            float kc[4] = {kv.x, kv.y, kv.z, kv.w};
#pragma unroll
            for (int j = 0; j < 4; ++j) {
                const int e = t4 * 4 + j;
                const float w = wv_r[e];
                float r0 = frcp(fexp2(qp_r[0][e] + kc[j]) + 1.0f);
                a0 = fmaf(w, r0, a0);
                float r1 = frcp(fexp2(qp_r[1][e] + kc[j]) + 1.0f);
                a1 = fmaf(w, r1, a1);
            }
        }
        s_red[wave][0][lane] = a0;
        s_red[wave][1][lane] = a1;
        __syncthreads();
        if (tid < 128) {
            const int q = tid >> 6, kl = tid & 63;
            float s = 0.f;
#pragma unroll
            for (int w = 0; w < 8; ++w) s += s_red[w][q][kl];
            s_sc[q][kt * 64 + kl] = -2.0f * s;
        }
    }
    __syncthreads();

    const int ntot = ntiles << 6;

    // ---- softmax over compacted scores: wave w < 2 handles q = w ----
    if (wave < 2) {
        const int q = wave;
        float mx = -3.0e38f;
        for (int j = lane; j < ntot; j += 64) {
            float s = (j < nv) ? s_sc[q][j] : -3.0e38f;
            mx = fmaxf(mx, s);
        }
#pragma unroll
        for (int off = 32; off > 0; off >>= 1) mx = fmaxf(mx, __shfl_xor(mx, off));
        float sum = 0.f;
        for (int j = lane; j < ntot; j += 64) {
            float s = (j < nv) ? s_sc[q][j] : -3.0e38f;
            float e = fexp2((s - mx) * 1.44269504f);
            s_sc[q][j] = e;
            sum += e;
        }
#pragma unroll
        for (int off = 32; off > 0; off >>= 1) sum += __shfl_xor(sum, off);
        const float inv = frcp(sum);
        for (int j = lane; j < ntot; j += 64) s_sc[q][j] *= inv;
    }
    __syncthreads();

    // ---- PV over compacted k: thread -> (d-float4 = tid&63, k-chunk = tid>>6) ----
    {
        const int dl = tid & 63;
        const int kq = tid >> 6;
        const int chunk = ntiles * 8;                 // ntot / 8
        float4 o0 = {0, 0, 0, 0}, o1 = {0, 0, 0, 0};
        const float4* v4 = (const float4*)(v + (size_t)b * K_ * D_);
        const int k0 = kq * chunk, k1 = k0 + chunk;
        for (int k = k0; k < k1; ++k) {
            int vr = s_kidx[k];                       // wave-uniform
            float4 vv = v4[(size_t)vr * 64 + dl];
            float p0 = s_sc[0][k], p1 = s_sc[1][k];
            o0.x = fmaf(p0, vv.x, o0.x); o0.y = fmaf(p0, vv.y, o0.y);
            o0.z = fmaf(p0, vv.z, o0.z); o0.w = fmaf(p0, vv.w, o0.w);
            o1.x = fmaf(p1, vv.x, o1.x); o1.y = fmaf(p1, vv.y, o1.y);
            o1.z = fmaf(p1, vv.z, o1.z); o1.w = fmaf(p1, vv.w, o1.w);
        }
        float4* s_pv = s_kp;                          // reuse, no alias with s_sc
        s_pv[(kq * 2 + 0) * 64 + dl] = o0;
        s_pv[(kq * 2 + 1) * 64 + dl] = o1;
        __syncthreads();
        if (tid < 128) {
            const int q = tid >> 6, c = tid & 63;
            float4 s = {0, 0, 0, 0};
#pragma unroll
            for (int g = 0; g < 8; ++g) {
                float4 x = s_pv[(g * 2 + q) * 64 + c];
                s.x += x.x; s.y += x.y; s.z += x.z; s.w += x.w;
            }
            *(float4*)(out + (size_t)(b * Q_ + q0 + q) * D_ + c * 4) = s;
        }
    }
}

extern "C" void kernel_launch(void* const* d_in, const int* in_sizes, int n_in,
                              void* d_out, int out_size, void* d_ws, size_t ws_size,
                              hipStream_t stream) {
    const float* q    = (const float*)d_in[0];
    const float* k    = (const float*)d_in[1];
    const float* v    = (const float*)d_in[2];
    const int*   mask = (const int*)d_in[3];
    const float* Wq   = (const float*)d_in[4];
    const float* Wk   = (const float*)d_in[5];
    const float* wv   = (const float*)d_in[6];
    float* out = (float*)d_out;

    float* qp = (float*)d_ws;                               // [B,Q,D]  1 MB
    float* kp = qp + (size_t)B_ * Q_ * D_;                  // [B,K,D]  4 MB
    ushort* kidx = (ushort*)(kp + (size_t)B_ * K_ * D_);    // [B,K]    8 KB
    int* nvalid = (int*)(kidx + (size_t)B_ * K_);           // [B]

    const float c2 = 2.885390082f;   // 2*log2(e): exp2((qp+kp)*c2) = e^(2(qp+kp))

    compact_kernel<<<B_, 64, 0, stream>>>(mask, kidx, nvalid);
    proj_kernel<<<dim3(B_ * Q_ / 64, 4), 256, 0, stream>>>(q, Wq, qp, c2);
    proj_kernel<<<dim3(B_ * K_ / 64, 4), 256, 0, stream>>>(k, Wk, kp, c2);
    attn_kernel<<<dim3(B_ * (Q_ / 2)), 512, 0, stream>>>(qp, kp, v, kidx, nvalid, wv, out);
}

// Round 5
// 82.583 us; speedup vs baseline: 1.5922x; 1.0858x over previous
//
#include <hip/hip_runtime.h>
#include <hip/hip_bf16.h>

#define B_ 4
#define Q_ 256
#define K_ 1024
#define D_ 256
#define LOG2E 1.44269504f

__device__ __forceinline__ float fexp2(float x) {
    float r; asm("v_exp_f32 %0, %1" : "=v"(r) : "v"(x)); return r;
}
__device__ __forceinline__ float frcp(float x) {
    float r; asm("v_rcp_f32 %0, %1" : "=v"(r) : "v"(x)); return r;
}

// Fused: blocks (x<80, y) do the two projections; blocks (80, y) do per-batch
// mask compaction (batch = y).
__global__ __launch_bounds__(256) void prep_kernel(const float* __restrict__ q,
                                                   const float* __restrict__ k,
                                                   const float* __restrict__ Wq,
                                                   const float* __restrict__ Wk,
                                                   const int* __restrict__ mask,
                                                   float* __restrict__ qp,
                                                   float* __restrict__ kp,
                                                   ushort* __restrict__ kidx,
                                                   int* __restrict__ nvalid,
                                                   float scale) {
    const int t = threadIdx.x;
    if (blockIdx.x >= 80) {
        // ---- compaction for batch b = blockIdx.y ----
        if (t >= 64) return;
        const int b = blockIdx.y, lane = t;
        const int* m = mask + b * K_;
        const int base = lane * 16;
        int cnt = 0;
#pragma unroll
        for (int i = 0; i < 16; ++i) cnt += (m[base + i] != 0);
        int inc = cnt;
#pragma unroll
        for (int d = 1; d < 64; d <<= 1) {
            int tt = __shfl_up(inc, d);
            if (lane >= d) inc += tt;
        }
        const int total = __shfl(inc, 63);
        int pos = inc - cnt;
        ushort* kb = kidx + b * K_;
        for (int i = 0; i < 16; ++i) {
            int kk = base + i;
            if (m[kk] != 0) kb[pos++] = (ushort)kk;
        }
        for (int j = total + lane; j < K_; j += 64) kb[j] = 0;
        if (lane == 0) nvalid[b] = total;
        return;
    }
    // ---- projection: out = scale * (A @ W) ----
    const float* A; const float* W; float* outp; int m0;
    if (blockIdx.x < 16) { A = q; W = Wq; outp = qp; m0 = blockIdx.x * 64; }
    else                 { A = k; W = Wk; outp = kp; m0 = (blockIdx.x - 16) * 64; }
    __shared__ float As[16][65];
    __shared__ float Ws[16][64];
    const int tx = t & 15, ty = t >> 4;
    const int n0 = blockIdx.y * 64;
    const int ar = t >> 2, ac = (t & 3) * 4;
    const int wr = t >> 4, wc = (t & 15) * 4;
    float c[4][4] = {};
    for (int kb = 0; kb < 256; kb += 16) {
        __syncthreads();
        float4 av = *(const float4*)(A + (size_t)(m0 + ar) * 256 + kb + ac);
        As[ac + 0][ar] = av.x; As[ac + 1][ar] = av.y;
        As[ac + 2][ar] = av.z; As[ac + 3][ar] = av.w;
        float4 wvv = *(const float4*)(W + (size_t)(kb + wr) * 256 + n0 + wc);
        wvv.x *= scale; wvv.y *= scale; wvv.z *= scale; wvv.w *= scale;
        *(float4*)(&Ws[wr][wc]) = wvv;
        __syncthreads();
#pragma unroll
        for (int kk = 0; kk < 16; ++kk) {
            float4 bv = *(const float4*)(&Ws[kk][tx * 4]);
#pragma unroll
            for (int i = 0; i < 4; ++i) {
                float a = As[kk][ty * 4 + i];
                c[i][0] = fmaf(a, bv.x, c[i][0]);
                c[i][1] = fmaf(a, bv.y, c[i][1]);
                c[i][2] = fmaf(a, bv.z, c[i][2]);
                c[i][3] = fmaf(a, bv.w, c[i][3]);
            }
        }
    }
#pragma unroll
    for (int i = 0; i < 4; ++i) {
        float4 o = make_float4(c[i][0], c[i][1], c[i][2], c[i][3]);
        *(float4*)(outp + (size_t)(m0 + ty * 4 + i) * 256 + n0 + tx * 4) = o;
    }
}

// Grid = 1024 = B * 128 qpairs * 2 k-halves. 512 threads = 8 waves.
// lane = (k-in-tile kl = lane&31, e-half eh = lane>>5). Wave w owns e-chunk
// [w*32, w*32+32); each lane handles 16 e's of it for 32 k's.
// Writes unnormalized partial (O, m, l) per (block, q) -> combine kernel.
__global__ __launch_bounds__(512, 6) void attn_kernel(const float* __restrict__ qp,
                                                      const float* __restrict__ kp,
                                                      const float* __restrict__ v,
                                                      const ushort* __restrict__ kidx_g,
                                                      const int* __restrict__ nvalid_g,
                                                      const float* __restrict__ wv,
                                                      float* __restrict__ O_part,
                                                      float* __restrict__ ml_part) {
    __shared__ union {
        struct { float4 kp4[32 * 65]; float red[8][2][32]; } sc;  // 35,328 B
        float4 pv[8 * 2 * 64];                                    // 16,384 B
    } u;
    __shared__ float  s_sc[2][512];     // 4 KB : unnormalized probs
    __shared__ ushort s_kidx[512];      // 1 KB

    const int tid  = threadIdx.x;
    const int lane = tid & 63;
    const int wave = tid >> 6;
    const int kl   = lane & 31;
    const int eh   = lane >> 5;

    int bid = blockIdx.x;
    bid = (bid & 7) * 128 + (bid >> 3);          // bijective XCD swizzle
    const int b  = bid >> 8;
    const int qi = (bid >> 1) & 127;
    const int h  = bid & 1;
    const int q0 = qi * 2;
    const int part = (b * 128 + qi) * 2 + h;

    const int nvs   = nvalid_g[b];
    const int half  = (nvs + 1) >> 1;
    const int kbase = h ? half : 0;
    const int range = h ? (nvs - half) : half;
    const int ntiles = (range + 31) >> 5;
    const int ntot   = ntiles << 5;

    for (int j = tid; j < ntot; j += 512)
        s_kidx[j] = (j < range) ? kidx_g[b * K_ + kbase + j] : (ushort)0;

    // per-lane registers: 16 e's of this wave's chunk
    float qp_r[2][16], wv_r[16];
    {
        const int e0 = wave * 32 + eh * 16;
#pragma unroll
        for (int qq = 0; qq < 2; ++qq) {
            const float4* p = (const float4*)(qp + ((size_t)(b * Q_ + q0 + qq) << 8) + e0);
#pragma unroll
            for (int i = 0; i < 4; ++i) {
                float4 x = p[i];
                qp_r[qq][i * 4 + 0] = x.x; qp_r[qq][i * 4 + 1] = x.y;
                qp_r[qq][i * 4 + 2] = x.z; qp_r[qq][i * 4 + 3] = x.w;
            }
        }
        const float4* pw = (const float4*)(wv + e0);
#pragma unroll
        for (int i = 0; i < 4; ++i) {
            float4 x = pw[i];
            wv_r[i * 4 + 0] = x.x; wv_r[i * 4 + 1] = x.y;
            wv_r[i * 4 + 2] = x.z; wv_r[i * 4 + 3] = x.w;
        }
    }
    __syncthreads();

    // ---- scores over 32-k tiles ----
    for (int kt = 0; kt < ntiles; ++kt) {
        {
            const float4* srcb = (const float4*)(kp + ((size_t)b * K_ << 8));
#pragma unroll
            for (int i = 0; i < 4; ++i) {
                int f = tid + i * 512;
                int row = f >> 6, col = f & 63;
                int gr = s_kidx[kt * 32 + row];
                u.sc.kp4[row * 65 + col] = srcb[((size_t)gr << 6) + col];
            }
        }
        __syncthreads();
        float a0 = 0.f, a1 = 0.f;
        const float4* krow = u.sc.kp4 + kl * 65 + wave * 8 + eh * 4;
#pragma unroll
        for (int t4 = 0; t4 < 4; ++t4) {
            float4 kv = krow[t4];
            float kc[4] = {kv.x, kv.y, kv.z, kv.w};
#pragma unroll
            for (int j = 0; j < 4; ++j) {
                const int e = t4 * 4 + j;
                const float w = wv_r[e];
                float r0 = frcp(fexp2(qp_r[0][e] + kc[j]) + 1.0f);
                a0 = fmaf(w, r0, a0);
                float r1 = frcp(fexp2(qp_r[1][e] + kc[j]) + 1.0f);
                a1 = fmaf(w, r1, a1);
            }
        }
        a0 += __shfl_xor(a0, 32);
        a1 += __shfl_xor(a1, 32);
        if (eh == 0) {
            u.sc.red[wave][0][kl] = a0;
            u.sc.red[wave][1][kl] = a1;
        }
        __syncthreads();
        if (tid < 64) {
            const int qq = tid >> 5, kk = tid & 31;
            float s = 0.f;
#pragma unroll
            for (int w = 0; w < 8; ++w) s += u.sc.red[w][qq][kk];
            const int idx = kt * 32 + kk;
            s_sc[qq][idx] = (idx < range) ? (-2.0f * s) : -3.0e38f;
        }
        __syncthreads();
    }

    // ---- local (unnormalized) softmax: wave qq < 2 handles q = qq ----
    if (wave < 2) {
        const int qq = wave;
        float mx = -3.0e38f;
        for (int j = lane; j < ntot; j += 64) mx = fmaxf(mx, s_sc[qq][j]);
#pragma unroll
        for (int off = 32; off > 0; off >>= 1) mx = fmaxf(mx, __shfl_xor(mx, off));
        float sum = 0.f;
        for (int j = lane; j < ntot; j += 64) {
            float e = fexp2((s_sc[qq][j] - mx) * LOG2E);
            s_sc[qq][j] = e;
            sum += e;
        }
#pragma unroll
        for (int off = 32; off > 0; off >>= 1) sum += __shfl_xor(sum, off);
        if (lane == 0) {
            ml_part[part * 4 + qq * 2 + 0] = mx;
            ml_part[part * 4 + qq * 2 + 1] = sum;
        }
    }
    __syncthreads();

    // ---- PV (unnormalized): thread -> (d-float4 = tid&63, k-chunk = tid>>6) ----
    {
        const int dl = tid & 63;
        const int kq = tid >> 6;
        const int chunk = ntiles * 4;
        float4 o0 = {0, 0, 0, 0}, o1 = {0, 0, 0, 0};
        const float4* v4 = (const float4*)(v + ((size_t)b * K_ << 8));
        for (int k = kq * chunk; k < kq * chunk + chunk; ++k) {
            int vr = s_kidx[k];
            float4 vv = v4[((size_t)vr << 6) + dl];
            float p0 = s_sc[0][k], p1 = s_sc[1][k];
            o0.x = fmaf(p0, vv.x, o0.x); o0.y = fmaf(p0, vv.y, o0.y);
            o0.z = fmaf(p0, vv.z, o0.z); o0.w = fmaf(p0, vv.w, o0.w);
            o1.x = fmaf(p1, vv.x, o1.x); o1.y = fmaf(p1, vv.y, o1.y);
            o1.z = fmaf(p1, vv.z, o1.z); o1.w = fmaf(p1, vv.w, o1.w);
        }
        u.pv[(kq * 2 + 0) * 64 + dl] = o0;
        u.pv[(kq * 2 + 1) * 64 + dl] = o1;
        __syncthreads();
        if (tid < 128) {
            const int qq = tid >> 6, c = tid & 63;
            float4 s = {0, 0, 0, 0};
#pragma unroll
            for (int g = 0; g < 8; ++g) {
                float4 x = u.pv[(g * 2 + qq) * 64 + c];
                s.x += x.x; s.y += x.y; s.z += x.z; s.w += x.w;
            }
            ((float4*)O_part)[((size_t)part * 2 + qq) * 64 + c] = s;
        }
    }
}

// Merge the two k-halves: out = (O0*e^(m0-m) + O1*e^(m1-m)) / (l0*e^(m0-m)+l1*e^(m1-m))
__global__ __launch_bounds__(128) void combine_kernel(const float* __restrict__ O_part,
                                                      const float* __restrict__ ml,
                                                      float* __restrict__ out) {
    const int bid = blockIdx.x;              // 512 = B * 128 qpairs
    const int b = bid >> 7, qi = bid & 127;
    const int p0 = (b * 128 + qi) * 2;
    const int t = threadIdx.x;
    const int qq = t >> 6, c = t & 63;
    float m0 = ml[p0 * 4 + qq * 2], l0 = ml[p0 * 4 + qq * 2 + 1];
    float m1 = ml[(p0 + 1) * 4 + qq * 2], l1 = ml[(p0 + 1) * 4 + qq * 2 + 1];
    float m = fmaxf(m0, m1);
    float s0 = fexp2((m0 - m) * LOG2E);
    float s1 = fexp2((m1 - m) * LOG2E);
    float inv = frcp(l0 * s0 + l1 * s1);
    const float4* O0 = (const float4*)O_part + ((size_t)p0 * 2 + qq) * 64;
    const float4* O1 = (const float4*)O_part + ((size_t)(p0 + 1) * 2 + qq) * 64;
    float4 a = O0[c], bb = O1[c];
    float4 r;
    r.x = (a.x * s0 + bb.x * s1) * inv;
    r.y = (a.y * s0 + bb.y * s1) * inv;
    r.z = (a.z * s0 + bb.z * s1) * inv;
    r.w = (a.w * s0 + bb.w * s1) * inv;
    ((float4*)out)[((size_t)(b * Q_ + qi * 2 + qq) << 6) + c] = r;
}

extern "C" void kernel_launch(void* const* d_in, const int* in_sizes, int n_in,
                              void* d_out, int out_size, void* d_ws, size_t ws_size,
                              hipStream_t stream) {
    const float* q    = (const float*)d_in[0];
    const float* k    = (const float*)d_in[1];
    const float* v    = (const float*)d_in[2];
    const int*   mask = (const int*)d_in[3];
    const float* Wq   = (const float*)d_in[4];
    const float* Wk   = (const float*)d_in[5];
    const float* wv   = (const float*)d_in[6];
    float* out = (float*)d_out;

    float* qp     = (float*)d_ws;                        // 1 MB
    float* kp     = qp + (size_t)B_ * Q_ * D_;           // 4 MB
    float* O_part = kp + (size_t)B_ * K_ * D_;           // 1024*2*256 f32 = 2 MB
    float* ml     = O_part + (size_t)1024 * 2 * D_;      // 4096 f32 = 16 KB
    ushort* kidx  = (ushort*)(ml + 4096);                // 8 KB
    int* nvalid   = (int*)(kidx + (size_t)B_ * K_);      // 16 B

    const float c2 = 2.885390082f;  // 2*log2(e)

    prep_kernel<<<dim3(81, 4), 256, 0, stream>>>(q, k, Wq, Wk, mask, qp, kp, kidx, nvalid, c2);
    attn_kernel<<<dim3(1024), 512, 0, stream>>>(qp, kp, v, kidx, nvalid, wv, O_part, ml);
    combine_kernel<<<dim3(512), 128, 0, stream>>>(O_part, ml, out);
}